// Round 4
// baseline (370.286 us; speedup 1.0000x reference)
//
#include <hip/hip_runtime.h>
#include <hip/hip_bf16.h>
#include <cmath>

#define SEQ  1024
#define DIM  1024
#define NH   16
#define HDIM 64

typedef __attribute__((ext_vector_type(8))) short bf16x8;   // 8 bf16 (4 VGPRs)
typedef __attribute__((ext_vector_type(4))) float f32x4;    // MFMA accumulator
typedef __attribute__((ext_vector_type(4))) unsigned int u32x4;
typedef __attribute__((ext_vector_type(8))) unsigned short u16x8;

static __device__ __forceinline__ unsigned short bf16_bits(float x) {
    __hip_bfloat16 h = __float2bfloat16(x);
    union { __hip_bfloat16 b; unsigned short u; } cv; cv.b = h; return cv.u;
}
static __device__ __forceinline__ float bf16_to_f(unsigned short u) {
    union { unsigned short u; __hip_bfloat16 b; } cv; cv.u = u; return __bfloat162float(cv.b);
}

static __device__ __forceinline__ void gload16(const void* g, void* l) {
    __builtin_amdgcn_global_load_lds(
        (const __attribute__((address_space(1))) void*)g,
        (__attribute__((address_space(3))) void*)l, 16, 0, 0);
}

// Fragment read from a [rows][64 bf16] LDS tile with chunk-XOR swizzle.
// dc = 32-elem k-chunk (0/1), g = lane>>4.  byte-in-row = 16*((4dc+g)^(row&7)).
// Bank check: 16 lanes of a g-group cover all 32 banks exactly 2x -> free.
static __device__ __forceinline__ bf16x8 ldsfrag(const char* base, int row, int dc, int g) {
    const int chunk = ((dc << 2) + g) ^ (row & 7);
    return *(const bf16x8*)(base + row * 128 + chunk * 16);
}

// ---------------------------------------------------------------------------
// Split fp32 -> (hi, lo) bf16 planes.  x == hi + lo to ~2^-16 rel.
// ---------------------------------------------------------------------------
__global__ __launch_bounds__(256) void split_kernel(
    const float4* __restrict__ src, ushort4* __restrict__ hi, ushort4* __restrict__ lo)
{
    const int i = blockIdx.x * 256 + threadIdx.x;
    const float4 v = src[i];
    ushort4 H, L;
    H.x = bf16_bits(v.x); L.x = bf16_bits(v.x - bf16_to_f(H.x));
    H.y = bf16_bits(v.y); L.y = bf16_bits(v.y - bf16_to_f(H.y));
    H.z = bf16_bits(v.z); L.z = bf16_bits(v.z - bf16_to_f(H.z));
    H.w = bf16_bits(v.w); L.w = bf16_bits(v.w - bf16_to_f(H.w));
    hi[i] = H; lo[i] = L;
}

// ---------------------------------------------------------------------------
// Transpose + split weights: W[k][n] fp32 -> Wt{hi,lo}[n][k] bf16.
// Output layout [z][hi|lo][1024][1024] in `base`.
// ---------------------------------------------------------------------------
__global__ __launch_bounds__(256) void wsplit_kernel(
    const float* __restrict__ Wq, const float* __restrict__ Wk,
    const float* __restrict__ Wv, const float* __restrict__ Wo,
    unsigned short* __restrict__ base)
{
    const int z = blockIdx.z;
    const float* __restrict__ W = (z == 0) ? Wq : (z == 1) ? Wk : (z == 2) ? Wv : Wo;
    unsigned short* __restrict__ hi = base + (size_t)z * 2097152;
    unsigned short* __restrict__ lo = hi + 1048576;
    const int k0 = blockIdx.y * 32, n0 = blockIdx.x * 32;
    __shared__ float Ts[32][33];
    const int t = threadIdx.x, r = t >> 5, c = t & 31;
#pragma unroll
    for (int s = 0; s < 4; ++s)
        Ts[r + 8 * s][c] = W[(size_t)(k0 + r + 8 * s) * DIM + n0 + c];
    __syncthreads();
#pragma unroll
    for (int s = 0; s < 4; ++s) {
        const int rr = r + 8 * s;            // n-local
        const float v = Ts[c][rr];           // = W[k0+c][n0+rr]
        const unsigned short h = bf16_bits(v);
        const unsigned short l = bf16_bits(v - bf16_to_f(h));
        hi[(size_t)(n0 + rr) * DIM + k0 + c] = h;
        lo[(size_t)(n0 + rr) * DIM + k0 + c] = l;
    }
}

// ---------------------------------------------------------------------------
// Split-bf16 MFMA GEMM, 128x128x32 tile, 4 waves (2x2), 16x16x32 bf16 MFMA.
// acc = Ahi*Bhi + Ahi*Blo + Alo*Bhi  (~1e-5 rel err; lo*lo term dropped).
// Epilogue (z<2): bias + (1+g*tanh(mag)) scale + phase rotation, out = hi/lo
// bf16 planes [B,H,L,64].  z==2: bias only, out = packed uint (hi|lo<<16).
// ---------------------------------------------------------------------------
__global__ __launch_bounds__(256) void qkv_gemm(
    const unsigned short* __restrict__ Xhi, const unsigned short* __restrict__ Xlo,
    const unsigned short* __restrict__ Wt,
    const float* __restrict__ bq, const float* __restrict__ bk, const float* __restrict__ bv,
    const float* __restrict__ phi, const float* __restrict__ mag,
    const float* __restrict__ gamma,
    unsigned short* __restrict__ qhi, unsigned short* __restrict__ qlo,
    unsigned short* __restrict__ khi, unsigned short* __restrict__ klo,
    unsigned int* __restrict__ vpack)
{
    const int z = blockIdx.z;
    const unsigned short* __restrict__ Bhi = Wt + (size_t)z * 2097152;
    const unsigned short* __restrict__ Blo = Bhi + 1048576;
    const float* __restrict__ bias = (z == 0) ? bq : (z == 1) ? bk : bv;

    const int n0 = blockIdx.x * 128, m0 = blockIdx.y * 128;
    const int tid = threadIdx.x, lane = tid & 63, wid = tid >> 6;
    const int wm = wid >> 1, wn = wid & 1;
    const int lm = lane & 15, g = lane >> 4;
    const int sel = (lane >> 1) & 3;                 // == (frag_row>>1)&3 since row%16==lm
    const int chunkoff = ((g ^ sel) << 4);

    __shared__ f32x4 smem_[2048];                    // 32 KB
    char* smem = (char*)smem_;

    f32x4 acc[4][4] = {};

    for (int k0 = 0; k0 < DIM; k0 += 32) {
#pragma unroll
        for (int t = 0; t < 8; ++t) {                // 4 tiles x 2 half-tiles
            const int tile = t >> 1;
            const int c = ((t & 1) << 8) + (wid << 6) + lane;   // chunk 0..511
            const int m = c >> 2, j = c & 3;
            const int kk = ((j ^ ((m >> 1) & 3)) << 3);          // inverse-swizzled source
            const unsigned short* srcrow =
                (tile == 0) ? Xhi + (size_t)(m0 + m) * DIM :
                (tile == 1) ? Xlo + (size_t)(m0 + m) * DIM :
                (tile == 2) ? Bhi + (size_t)(n0 + m) * DIM :
                              Blo + (size_t)(n0 + m) * DIM;
            gload16(srcrow + k0 + kk,
                    smem + (tile << 13) + ((((t & 1) << 8) + (wid << 6)) << 4));
        }
        __syncthreads();                             // tiles ready (vmcnt drained)

        bf16x8 ah[4], al[4], bh[4], bl[4];
#pragma unroll
        for (int f = 0; f < 4; ++f) {
            const int offA = (((wm << 6) + (f << 4) + lm) << 6) + chunkoff;
            const int offB = (((wn << 6) + (f << 4) + lm) << 6) + chunkoff;
            ah[f] = *(const bf16x8*)(smem + offA);
            al[f] = *(const bf16x8*)(smem + 8192 + offA);
            bh[f] = *(const bf16x8*)(smem + 16384 + offB);
            bl[f] = *(const bf16x8*)(smem + 24576 + offB);
        }
#pragma unroll
        for (int i = 0; i < 4; ++i)
#pragma unroll
            for (int j = 0; j < 4; ++j) {
                acc[i][j] = __builtin_amdgcn_mfma_f32_16x16x32_bf16(ah[i], bh[j], acc[i][j], 0, 0, 0);
                acc[i][j] = __builtin_amdgcn_mfma_f32_16x16x32_bf16(ah[i], bl[j], acc[i][j], 0, 0, 0);
                acc[i][j] = __builtin_amdgcn_mfma_f32_16x16x32_bf16(al[i], bh[j], acc[i][j], 0, 0, 0);
            }
        __syncthreads();                             // reads done before next staging
    }

    // ---- epilogue ----
    const int bb = m0 >> 10, l0g = m0 & 1023, h0 = n0 >> 6;
    const int h = h0 + wn;                           // one wave-column = one head
    float* smf = (float*)smem;

    if (z < 2) {
        unsigned short* __restrict__ outhi = (z == 0) ? qhi : khi;
        unsigned short* __restrict__ outlo = (z == 0) ? qlo : klo;
        {   // per-row cos/sin/scale for both heads of this block
            const int row = tid & 127, hh = tid >> 7;
            const size_t pidx = ((size_t)(bb * NH + h0 + hh)) * SEQ + l0g + row;
            float s_, c_;
            sincosf(phi[pidx], &s_, &c_);
            smf[(hh << 7) + row] = c_;
            smf[256 + (hh << 7) + row] = s_;
            smf[512 + (hh << 7) + row] = 1.0f + gamma[h0 + hh] * tanhf(mag[pidx]);
        }
        __syncthreads();
        const size_t obase = (size_t)(bb * NH + h) * SEQ + l0g;
#pragma unroll
        for (int i = 0; i < 4; ++i)
#pragma unroll
            for (int r = 0; r < 4; ++r) {
                const int rowl = (wm << 6) + (i << 4) + (g << 2) + r;  // 0..127
                const float c_ = smf[(wn << 7) + rowl];
                const float s_ = smf[256 + (wn << 7) + rowl];
                const float sc = smf[512 + (wn << 7) + rowl];
                const size_t orow = (obase + rowl) * HDIM;
#pragma unroll
                for (int j = 0; j < 2; ++j) {        // d and d+32 = frags j, j+2
                    const int d = (j << 4) + lm;     // 0..31
                    const int n1 = n0 + (wn << 6) + d;
                    const float x1 = (acc[i][j][r] + bias[n1]) * sc;
                    const float x2 = (acc[i][j + 2][r] + bias[n1 + 32]) * sc;
                    const float o1 = x1 * c_ - x2 * s_;
                    const float o2 = x2 * c_ + x1 * s_;
                    const unsigned short h1 = bf16_bits(o1);
                    const unsigned short h2 = bf16_bits(o2);
                    outhi[orow + d]      = h1;
                    outlo[orow + d]      = bf16_bits(o1 - bf16_to_f(h1));
                    outhi[orow + d + 32] = h2;
                    outlo[orow + d + 32] = bf16_bits(o2 - bf16_to_f(h2));
                }
            }
    } else {
        const size_t obase = (size_t)(bb * NH + h) * SEQ + l0g;
#pragma unroll
        for (int i = 0; i < 4; ++i)
#pragma unroll
            for (int r = 0; r < 4; ++r) {
                const int rowl = (wm << 6) + (i << 4) + (g << 2) + r;
                const size_t orow = (obase + rowl) * HDIM;
#pragma unroll
                for (int j = 0; j < 4; ++j) {
                    const int d = (j << 4) + lm;     // 0..63
                    const float val = acc[i][j][r] + bias[n0 + (wn << 6) + d];
                    const unsigned short hv = bf16_bits(val);
                    const unsigned short lv = bf16_bits(val - bf16_to_f(hv));
                    vpack[orow + d] = (unsigned int)hv | ((unsigned int)lv << 16);
                }
            }
    }
}

// ---------------------------------------------------------------------------
// Global V transpose: vpack [bh][l][64] uint -> vthi/vtlo [bh][64][L] bf16.
// LDS-transposed so both global read and write are 16B coalesced.
// ---------------------------------------------------------------------------
__global__ __launch_bounds__(256) void vtrans_kernel(
    const unsigned int* __restrict__ vpack,
    unsigned short* __restrict__ vthi, unsigned short* __restrict__ vtlo)
{
    const int lt = blockIdx.x;    // 0..15 (l-tile)
    const int bh = blockIdx.y;    // 0..63
    __shared__ unsigned int Ts[64][65];
    const int t = threadIdx.x;
    const int row = t >> 2, c0 = (t & 3) << 4;   // row = l-local, c0 = d0
    const unsigned int* __restrict__ src =
        vpack + ((size_t)bh * SEQ + lt * 64 + row) * HDIM + c0;
#pragma unroll
    for (int i = 0; i < 4; ++i) {
        const u32x4 v = *(const u32x4*)(src + i * 4);
        Ts[row][c0 + i * 4 + 0] = v.x;
        Ts[row][c0 + i * 4 + 1] = v.y;
        Ts[row][c0 + i * 4 + 2] = v.z;
        Ts[row][c0 + i * 4 + 3] = v.w;
    }
    __syncthreads();
    const int dl = t >> 2, lc0 = (t & 3) << 4;   // dl = d-local, lc0 = l-local
    u16x8 h0, h1, l0v, l1v;
#pragma unroll
    for (int e = 0; e < 8; ++e) {
        const unsigned int u = Ts[lc0 + e][dl];
        h0[e]  = (unsigned short)(u & 0xffff);
        l0v[e] = (unsigned short)(u >> 16);
    }
#pragma unroll
    for (int e = 0; e < 8; ++e) {
        const unsigned int u = Ts[lc0 + 8 + e][dl];
        h1[e]  = (unsigned short)(u & 0xffff);
        l1v[e] = (unsigned short)(u >> 16);
    }
    const size_t orow = ((size_t)bh * HDIM + dl) * SEQ + lt * 64 + lc0;
    *(u16x8*)(vthi + orow)     = h0;
    *(u16x8*)(vthi + orow + 8) = h1;
    *(u16x8*)(vtlo + orow)     = l0v;
    *(u16x8*)(vtlo + orow + 8) = l1v;
}

// ---------------------------------------------------------------------------
// Flash attention on MFMA (split-bf16 QK^T and PV).
// Block = (q-tile of 64 rows) x (b,h).  4 waves x 16 q-rows, barrier-free
// between staging barriers -> waves at independent phases (T5 regime).
// K/V^T tiles staged via global_load_lds (linear dest, swizzled source).
// P goes through per-wave private LDS (packed hi|lo uint) to reach A-layout.
// ---------------------------------------------------------------------------
#define A_KHI 0
#define A_KLO 8192
#define A_VTH 16384
#define A_VTL 24576
#define A_P   32768          // + wid*4352 ; stride 68 uints per q-row

__global__ __launch_bounds__(256) void attn_mfma(
    const unsigned short* __restrict__ qhi, const unsigned short* __restrict__ qlo,
    const unsigned short* __restrict__ khi, const unsigned short* __restrict__ klo,
    const unsigned short* __restrict__ vthi, const unsigned short* __restrict__ vtlo,
    const float* __restrict__ mask,
    unsigned short* __restrict__ ctxhi, unsigned short* __restrict__ ctxlo)
{
    const int qt = blockIdx.x;        // 0..15
    const int bh = blockIdx.y;        // 0..63
    const int b = bh >> 4, h = bh & 15;
    const int tid = threadIdx.x, lane = tid & 63, wid = tid >> 6;
    const int lm = lane & 15, g = lane >> 4;

    __shared__ __align__(16) char smem[50176];
    unsigned int* pw = (unsigned int*)(smem + A_P + wid * 4352);

    // Q fragments (held for the whole block): rows q = wid*16 + lm
    bf16x8 qh[2], ql[2];
    {
        const size_t qr = ((size_t)bh * SEQ + qt * 64 + wid * 16 + lm) * HDIM;
#pragma unroll
        for (int c = 0; c < 2; ++c) {
            qh[c] = *(const bf16x8*)(qhi + qr + c * 32 + g * 8);
            ql[c] = *(const bf16x8*)(qlo + qr + c * 32 + g * 8);
        }
    }

    f32x4 caf[4] = {};                           // ctx d-frags
    float mrow[4] = {-3.0e38f, -3.0e38f, -3.0e38f, -3.0e38f};
    float lrow[4] = {};

    for (int kt = 0; kt < 16; ++kt) {
        __syncthreads();                         // previous tile reads done
#pragma unroll
        for (int s = 0; s < 8; ++s) {            // stage Khi,Klo,Vthi,Vtlo (8KB each)
            const int tile = s >> 1;
            const int c = ((s & 1) << 8) + tid;  // chunk 0..511
            const int row = c >> 3, ch = c & 7;
            const int sc = ch ^ (row & 7);       // inverse swizzle on source
            const unsigned short* src =
                (tile == 0) ? khi + ((size_t)bh * SEQ + kt * 64 + row) * HDIM + sc * 8 :
                (tile == 1) ? klo + ((size_t)bh * SEQ + kt * 64 + row) * HDIM + sc * 8 :
                (tile == 2) ? vthi + ((size_t)bh * HDIM + row) * SEQ + kt * 64 + sc * 8 :
                              vtlo + ((size_t)bh * HDIM + row) * SEQ + kt * 64 + sc * 8;
            gload16(src, smem + (tile << 13) + ((c & ~63) << 4));
        }
        __syncthreads();                         // tiles ready

        // ---- S = Q K^T (split-bf16), S[q=g*4+r][kv=f*16+lm] ----
        f32x4 sf[4];
        __builtin_amdgcn_s_setprio(1);           // T5: favor MFMA wave (m191 +4-7%)
#pragma unroll
        for (int f = 0; f < 4; ++f) {
            f32x4 s = {};
#pragma unroll
            for (int c = 0; c < 2; ++c) {
                const bf16x8 kh = ldsfrag(smem + A_KHI, f * 16 + lm, c, g);
                const bf16x8 kl = ldsfrag(smem + A_KLO, f * 16 + lm, c, g);
                s = __builtin_amdgcn_mfma_f32_16x16x32_bf16(qh[c], kh, s, 0, 0, 0);
                s = __builtin_amdgcn_mfma_f32_16x16x32_bf16(qh[c], kl, s, 0, 0, 0);
                s = __builtin_amdgcn_mfma_f32_16x16x32_bf16(ql[c], kh, s, 0, 0, 0);
            }
            sf[f] = s;
        }
        __builtin_amdgcn_s_setprio(0);

        // ---- online softmax (rows q = g*4+r; cols f*16+lm) ----
        float mv[4];
#pragma unroll
        for (int f = 0; f < 4; ++f)
            mv[f] = mask[(size_t)b * SEQ + kt * 64 + f * 16 + lm];

        float sc_[4][4];
#pragma unroll
        for (int f = 0; f < 4; ++f)
#pragma unroll
            for (int r = 0; r < 4; ++r)
                sc_[f][r] = sf[f][r] * 0.125f + mv[f];

#pragma unroll
        for (int r = 0; r < 4; ++r) {
            float rm = fmaxf(fmaxf(sc_[0][r], sc_[1][r]), fmaxf(sc_[2][r], sc_[3][r]));
            rm = fmaxf(rm, __shfl_xor(rm, 1));
            rm = fmaxf(rm, __shfl_xor(rm, 2));
            rm = fmaxf(rm, __shfl_xor(rm, 4));
            rm = fmaxf(rm, __shfl_xor(rm, 8));
            const float mnew = fmaxf(mrow[r], rm);
            const float corr = __expf(mrow[r] - mnew);
            float p[4], sum = 0.f;
#pragma unroll
            for (int f = 0; f < 4; ++f) { p[f] = __expf(sc_[f][r] - mnew); sum += p[f]; }
            sum += __shfl_xor(sum, 1);
            sum += __shfl_xor(sum, 2);
            sum += __shfl_xor(sum, 4);
            sum += __shfl_xor(sum, 8);
            lrow[r] = lrow[r] * corr + sum;
            mrow[r] = mnew;
#pragma unroll
            for (int df = 0; df < 4; ++df) caf[df][r] *= corr;
#pragma unroll
            for (int f = 0; f < 4; ++f) {
                const unsigned short hv = bf16_bits(p[f]);
                const unsigned short lv = bf16_bits(p[f] - bf16_to_f(hv));
                pw[(g * 4 + r) * 68 + f * 16 + lm] =
                    (unsigned int)hv | ((unsigned int)lv << 16);
            }
        }

        // ---- P fragments (A-layout): row q = lm, kv = c*32 + g*8 + e ----
        bf16x8 ph[2], pl[2];
#pragma unroll
        for (int c = 0; c < 2; ++c) {
            const unsigned int* pr = pw + lm * 68 + c * 32 + g * 8;
            const u32x4 u0 = *(const u32x4*)pr;
            const u32x4 u1 = *(const u32x4*)(pr + 4);
            bf16x8 hh, ll;
            hh[0] = (short)(u0.x & 0xffff); ll[0] = (short)(u0.x >> 16);
            hh[1] = (short)(u0.y & 0xffff); ll[1] = (short)(u0.y >> 16);
            hh[2] = (short)(u0.z & 0xffff); ll[2] = (short)(u0.z >> 16);
            hh[3] = (short)(u0.w & 0xffff); ll[3] = (short)(u0.w >> 16);
            hh[4] = (short)(u1.x & 0xffff); ll[4] = (short)(u1.x >> 16);
            hh[5] = (short)(u1.y & 0xffff); ll[5] = (short)(u1.y >> 16);
            hh[6] = (short)(u1.z & 0xffff); ll[6] = (short)(u1.z >> 16);
            hh[7] = (short)(u1.w & 0xffff); ll[7] = (short)(u1.w >> 16);
            ph[c] = hh; pl[c] = ll;
        }

        // ---- ctx += P V (split-bf16) ----
        __builtin_amdgcn_s_setprio(1);
#pragma unroll
        for (int df = 0; df < 4; ++df)
#pragma unroll
            for (int c = 0; c < 2; ++c) {
                const bf16x8 vh = ldsfrag(smem + A_VTH, df * 16 + lm, c, g);
                const bf16x8 vl = ldsfrag(smem + A_VTL, df * 16 + lm, c, g);
                caf[df] = __builtin_amdgcn_mfma_f32_16x16x32_bf16(ph[c], vh, caf[df], 0, 0, 0);
                caf[df] = __builtin_amdgcn_mfma_f32_16x16x32_bf16(ph[c], vl, caf[df], 0, 0, 0);
                caf[df] = __builtin_amdgcn_mfma_f32_16x16x32_bf16(pl[c], vh, caf[df], 0, 0, 0);
            }
        __builtin_amdgcn_s_setprio(0);
    }

    // ---- write ctx (hi/lo planes, [B,L,D] with heads merged) ----
#pragma unroll
    for (int r = 0; r < 4; ++r) {
        const float inv = 1.0f / lrow[r];
        const size_t orow =
            ((size_t)b * SEQ + qt * 64 + wid * 16 + g * 4 + r) * DIM + h * HDIM;
#pragma unroll
        for (int df = 0; df < 4; ++df) {
            const float o = caf[df][r] * inv;
            const unsigned short hv = bf16_bits(o);
            ctxhi[orow + df * 16 + lm] = hv;
            ctxlo[orow + df * 16 + lm] = bf16_bits(o - bf16_to_f(hv));
        }
    }
}

// ---------------------------------------------------------------------------
// Out-projection GEMM: x = ctx @ Wo + bo + resid, flat [4096][1024].
// ---------------------------------------------------------------------------
__global__ __launch_bounds__(256) void out_gemm(
    const unsigned short* __restrict__ Ahi, const unsigned short* __restrict__ Alo,
    const unsigned short* __restrict__ Bhi, const unsigned short* __restrict__ Blo,
    const float* __restrict__ bo, const float* __restrict__ resid,
    float* __restrict__ xout)
{
    const int n0 = blockIdx.x * 128, m0 = blockIdx.y * 128;
    const int tid = threadIdx.x, lane = tid & 63, wid = tid >> 6;
    const int wm = wid >> 1, wn = wid & 1;
    const int lm = lane & 15, g = lane >> 4;
    const int sel = (lane >> 1) & 3;
    const int chunkoff = ((g ^ sel) << 4);

    __shared__ f32x4 smem_[2048];
    char* smem = (char*)smem_;

    f32x4 acc[4][4] = {};

    for (int k0 = 0; k0 < DIM; k0 += 32) {
#pragma unroll
        for (int t = 0; t < 8; ++t) {
            const int tile = t >> 1;
            const int c = ((t & 1) << 8) + (wid << 6) + lane;
            const int m = c >> 2, j = c & 3;
            const int kk = ((j ^ ((m >> 1) & 3)) << 3);
            const unsigned short* srcrow =
                (tile == 0) ? Ahi + (size_t)(m0 + m) * DIM :
                (tile == 1) ? Alo + (size_t)(m0 + m) * DIM :
                (tile == 2) ? Bhi + (size_t)(n0 + m) * DIM :
                              Blo + (size_t)(n0 + m) * DIM;
            gload16(srcrow + k0 + kk,
                    smem + (tile << 13) + ((((t & 1) << 8) + (wid << 6)) << 4));
        }
        __syncthreads();

        bf16x8 ah[4], al[4], bh[4], bl[4];
#pragma unroll
        for (int f = 0; f < 4; ++f) {
            const int offA = (((wm << 6) + (f << 4) + lm) << 6) + chunkoff;
            const int offB = (((wn << 6) + (f << 4) + lm) << 6) + chunkoff;
            ah[f] = *(const bf16x8*)(smem + offA);
            al[f] = *(const bf16x8*)(smem + 8192 + offA);
            bh[f] = *(const bf16x8*)(smem + 16384 + offB);
            bl[f] = *(const bf16x8*)(smem + 24576 + offB);
        }
#pragma unroll
        for (int i = 0; i < 4; ++i)
#pragma unroll
            for (int j = 0; j < 4; ++j) {
                acc[i][j] = __builtin_amdgcn_mfma_f32_16x16x32_bf16(ah[i], bh[j], acc[i][j], 0, 0, 0);
                acc[i][j] = __builtin_amdgcn_mfma_f32_16x16x32_bf16(ah[i], bl[j], acc[i][j], 0, 0, 0);
                acc[i][j] = __builtin_amdgcn_mfma_f32_16x16x32_bf16(al[i], bh[j], acc[i][j], 0, 0, 0);
            }
        __syncthreads();
    }

#pragma unroll
    for (int i = 0; i < 4; ++i)
#pragma unroll
        for (int r = 0; r < 4; ++r) {
            const int mrow = m0 + (wm << 6) + (i << 4) + (g << 2) + r;
#pragma unroll
            for (int j = 0; j < 4; ++j) {
                const int n1 = n0 + (wn << 6) + (j << 4) + lm;
                xout[(size_t)mrow * DIM + n1] =
                    acc[i][j][r] + bo[n1] + resid[(size_t)mrow * DIM + n1];
            }
        }
}

// ---------------------------------------------------------------------------
// LayerNorm over D=1024, one row per block.
// ---------------------------------------------------------------------------
__global__ __launch_bounds__(256) void ln_kernel(
    const float* __restrict__ x, const float* __restrict__ g,
    const float* __restrict__ bta, float* __restrict__ out)
{
    const int row = blockIdx.x;
    const int tid = threadIdx.x;
    const float4 xv = ((const float4*)(x + (size_t)row * DIM))[tid];
    float s  = xv.x + xv.y + xv.z + xv.w;
    float s2 = xv.x * xv.x + xv.y * xv.y + xv.z * xv.z + xv.w * xv.w;
#pragma unroll
    for (int off = 1; off < 64; off <<= 1) {
        s  += __shfl_xor(s, off, 64);
        s2 += __shfl_xor(s2, off, 64);
    }
    __shared__ float red[8];
    const int wv = tid >> 6;
    if ((tid & 63) == 0) { red[wv] = s; red[wv + 4] = s2; }
    __syncthreads();
    s  = red[0] + red[1] + red[2] + red[3];
    s2 = red[4] + red[5] + red[6] + red[7];
    const float mu   = s * (1.0f / DIM);
    const float var  = s2 * (1.0f / DIM) - mu * mu;
    const float rstd = 1.0f / sqrtf(var + 1e-12f);
    const float4 gv = ((const float4*)g)[tid];
    const float4 bv = ((const float4*)bta)[tid];
    float4 o;
    o.x = (xv.x - mu) * rstd * gv.x + bv.x;
    o.y = (xv.y - mu) * rstd * gv.y + bv.y;
    o.z = (xv.z - mu) * rstd * gv.z + bv.z;
    o.w = (xv.w - mu) * rstd * gv.w + bv.w;
    ((float4*)(out + (size_t)row * DIM))[tid] = o;
}

// ---------------------------------------------------------------------------
extern "C" void kernel_launch(void* const* d_in, const int* in_sizes, int n_in,
                              void* d_out, int out_size, void* d_ws, size_t ws_size,
                              hipStream_t stream)
{
    const float* X     = (const float*)d_in[0];
    const float* mask  = (const float*)d_in[1];
    const float* phi   = (const float*)d_in[2];
    const float* mag   = (const float*)d_in[3];
    const float* Wq    = (const float*)d_in[4];
    const float* bq    = (const float*)d_in[5];
    const float* Wk    = (const float*)d_in[6];
    const float* bk    = (const float*)d_in[7];
    const float* Wv    = (const float*)d_in[8];
    const float* bv    = (const float*)d_in[9];
    const float* gamma = (const float*)d_in[10];
    const float* Wo    = (const float*)d_in[11];
    const float* bo    = (const float*)d_in[12];
    const float* lsc   = (const float*)d_in[13];
    const float* lbi   = (const float*)d_in[14];
    float* out = (float*)d_out;

    char* w = (char*)d_ws;
    const size_t MB = 1048576;
    unsigned short* qhi   = (unsigned short*)(w + 0 * MB);    // 8 MB each
    unsigned short* qlo   = (unsigned short*)(w + 8 * MB);
    unsigned short* khi   = (unsigned short*)(w + 16 * MB);
    unsigned short* klo   = (unsigned short*)(w + 24 * MB);
    unsigned int*   vpack = (unsigned int*)  (w + 32 * MB);   // 16 MB
    float*          xbuf  = (float*)         (w + 32 * MB);   // aliases vpack (dead by then)
    unsigned short* vthi  = (unsigned short*)(w + 48 * MB);
    unsigned short* vtlo  = (unsigned short*)(w + 56 * MB);
    unsigned short* Xhi   = (unsigned short*)(w + 64 * MB);
    unsigned short* Xlo   = (unsigned short*)(w + 72 * MB);
    unsigned short* ctxhi = Xhi;                              // aliases (X split dead)
    unsigned short* ctxlo = Xlo;
    unsigned short* Wt    = (unsigned short*)(w + 80 * MB);   // 16 MB

    const dim3 blk(256);
    split_kernel<<<4096, blk, 0, stream>>>((const float4*)X, (ushort4*)Xhi, (ushort4*)Xlo);
    wsplit_kernel<<<dim3(32, 32, 4), blk, 0, stream>>>(Wq, Wk, Wv, Wo, Wt);
    qkv_gemm<<<dim3(8, 32, 3), blk, 0, stream>>>(
        Xhi, Xlo, Wt, bq, bk, bv, phi, mag, gamma, qhi, qlo, khi, klo, vpack);
    vtrans_kernel<<<dim3(16, 64), blk, 0, stream>>>(vpack, vthi, vtlo);
    attn_mfma<<<dim3(16, 64), blk, 0, stream>>>(
        qhi, qlo, khi, klo, vthi, vtlo, mask, ctxhi, ctxlo);
    out_gemm<<<dim3(8, 32), blk, 0, stream>>>(
        ctxhi, ctxlo, Wt + 6 * 1048576, Wt + 7 * 1048576, bo, X, xbuf);
    ln_kernel<<<4096, blk, 0, stream>>>(xbuf, lsc, lbi, out);
}

// Round 5
// 343.391 us; speedup vs baseline: 1.0783x; 1.0783x over previous
//
#include <hip/hip_runtime.h>
#include <hip/hip_bf16.h>
#include <cmath>

#define SEQ  1024
#define DIM  1024
#define NH   16
#define HDIM 64

typedef __attribute__((ext_vector_type(8))) short bf16x8;   // 8 bf16 (4 VGPRs)
typedef __attribute__((ext_vector_type(4))) float f32x4;    // MFMA accumulator
typedef __attribute__((ext_vector_type(4))) unsigned int u32x4;
typedef __attribute__((ext_vector_type(8))) unsigned short u16x8;

static __device__ __forceinline__ unsigned short bf16_bits(float x) {
    __hip_bfloat16 h = __float2bfloat16(x);
    union { __hip_bfloat16 b; unsigned short u; } cv; cv.b = h; return cv.u;
}
static __device__ __forceinline__ float bf16_to_f(unsigned short u) {
    union { unsigned short u; __hip_bfloat16 b; } cv; cv.u = u; return __bfloat162float(cv.b);
}

static __device__ __forceinline__ void gload16(const void* g, void* l) {
    __builtin_amdgcn_global_load_lds(
        (const __attribute__((address_space(1))) void*)g,
        (__attribute__((address_space(3))) void*)l, 16, 0, 0);
}

// Fragment read from a [rows][32 bf16] GEMM LDS tile (64B rows, 4x16B chunks),
// chunk-XOR swizzled: stored position p holds source chunk p^((row>>1)&3).
// Verified on HW: SQ_LDS_BANK_CONFLICT == 0 (round 4).
// (attn uses the [rows][64 bf16] variant below.)
static __device__ __forceinline__ bf16x8 ldsfrag(const char* base, int row, int dc, int g) {
    const int chunk = ((dc << 2) + g) ^ (row & 7);
    return *(const bf16x8*)(base + row * 128 + chunk * 16);
}

// ---------------------------------------------------------------------------
// Split fp32 -> (hi, lo) bf16 planes.  x == hi + lo to ~2^-16 rel.
// ---------------------------------------------------------------------------
__global__ __launch_bounds__(256) void split_kernel(
    const float4* __restrict__ src, ushort4* __restrict__ hi, ushort4* __restrict__ lo)
{
    const int i = blockIdx.x * 256 + threadIdx.x;
    const float4 v = src[i];
    ushort4 H, L;
    H.x = bf16_bits(v.x); L.x = bf16_bits(v.x - bf16_to_f(H.x));
    H.y = bf16_bits(v.y); L.y = bf16_bits(v.y - bf16_to_f(H.y));
    H.z = bf16_bits(v.z); L.z = bf16_bits(v.z - bf16_to_f(H.z));
    H.w = bf16_bits(v.w); L.w = bf16_bits(v.w - bf16_to_f(H.w));
    hi[i] = H; lo[i] = L;
}

// ---------------------------------------------------------------------------
// Transpose + split weights: W[k][n] fp32 -> Wt{hi,lo}[n][k] bf16.
// Output layout [z][hi|lo][1024][1024] in `base`.
// ---------------------------------------------------------------------------
__global__ __launch_bounds__(256) void wsplit_kernel(
    const float* __restrict__ Wq, const float* __restrict__ Wk,
    const float* __restrict__ Wv, const float* __restrict__ Wo,
    unsigned short* __restrict__ base)
{
    const int z = blockIdx.z;
    const float* __restrict__ W = (z == 0) ? Wq : (z == 1) ? Wk : (z == 2) ? Wv : Wo;
    unsigned short* __restrict__ hi = base + (size_t)z * 2097152;
    unsigned short* __restrict__ lo = hi + 1048576;
    const int k0 = blockIdx.y * 32, n0 = blockIdx.x * 32;
    __shared__ float Ts[32][33];
    const int t = threadIdx.x, r = t >> 5, c = t & 31;
#pragma unroll
    for (int s = 0; s < 4; ++s)
        Ts[r + 8 * s][c] = W[(size_t)(k0 + r + 8 * s) * DIM + n0 + c];
    __syncthreads();
#pragma unroll
    for (int s = 0; s < 4; ++s) {
        const int rr = r + 8 * s;            // n-local
        const float v = Ts[c][rr];           // = W[k0+c][n0+rr]
        const unsigned short h = bf16_bits(v);
        const unsigned short l = bf16_bits(v - bf16_to_f(h));
        hi[(size_t)(n0 + rr) * DIM + k0 + c] = h;
        lo[(size_t)(n0 + rr) * DIM + k0 + c] = l;
    }
}

// ---------------------------------------------------------------------------
// Split-bf16 MFMA GEMM, 128x128x32 block tile, **8 waves (4m x 2n)**,
// wave tile 32x64, acc = 2x4 frags (32 AGPR).  16x16x32 bf16 MFMA.
// acc = Ahi*Bhi + Ahi*Blo + Alo*Bhi  (~1e-5 rel err).
// Round-5 change: 4->8 waves/block halves per-wave AGPR so unified regs
// fit 4 waves/SIMD (was 2: 112 VGPR + 64 AGPR = 176 -> occupancy 16%).
// Epilogue (z<2): bias + (1+g*tanh(mag)) scale + phase rotation, out = hi/lo
// bf16 planes [B,H,L,64].  z==2: bias only, out = packed uint (hi|lo<<16).
// ---------------------------------------------------------------------------
__global__ __launch_bounds__(512, 4) void qkv_gemm(
    const unsigned short* __restrict__ Xhi, const unsigned short* __restrict__ Xlo,
    const unsigned short* __restrict__ Wt,
    const float* __restrict__ bq, const float* __restrict__ bk, const float* __restrict__ bv,
    const float* __restrict__ phi, const float* __restrict__ mag,
    const float* __restrict__ gamma,
    unsigned short* __restrict__ qhi, unsigned short* __restrict__ qlo,
    unsigned short* __restrict__ khi, unsigned short* __restrict__ klo,
    unsigned int* __restrict__ vpack)
{
    const int z = blockIdx.z;
    const unsigned short* __restrict__ Bhi = Wt + (size_t)z * 2097152;
    const unsigned short* __restrict__ Blo = Bhi + 1048576;
    const float* __restrict__ bias = (z == 0) ? bq : (z == 1) ? bk : bv;

    const int n0 = blockIdx.x * 128, m0 = blockIdx.y * 128;
    const int tid = threadIdx.x, lane = tid & 63, wid = tid >> 6;   // wid 0..7
    const int wm = wid >> 1, wn = wid & 1;        // wm 0..3 (32-row strip), wn 0..1 (64-col)
    const int lm = lane & 15, g = lane >> 4;
    const int sel = (lane >> 1) & 3;              // == (frag_row>>1)&3 since row%16==lm
    const int chunkoff = ((g ^ sel) << 4);

    __shared__ f32x4 smem_[2048];                 // 32 KB
    char* smem = (char*)smem_;

    f32x4 acc[2][4] = {};

    // staging: 4 tiles x 512 chunks(16B); thread tid -> chunk tid of each tile.
    const int sm = tid >> 2, sj = tid & 3;        // row 0..127, chunk-in-row 0..3
    const int skk = ((sj ^ ((sm >> 1) & 3)) << 3);  // inverse-swizzled source k-off
    const int sdst = (wid << 10);                 // wave-uniform dest base (lane*16 implicit)

    for (int k0 = 0; k0 < DIM; k0 += 32) {
#pragma unroll
        for (int t = 0; t < 4; ++t) {
            const unsigned short* srcrow =
                (t == 0) ? Xhi + (size_t)(m0 + sm) * DIM :
                (t == 1) ? Xlo + (size_t)(m0 + sm) * DIM :
                (t == 2) ? Bhi + (size_t)(n0 + sm) * DIM :
                           Blo + (size_t)(n0 + sm) * DIM;
            gload16(srcrow + k0 + skk, smem + (t << 13) + sdst);
        }
        __syncthreads();                          // tiles ready (vmcnt drained)

        bf16x8 ah[2], al[2], bh[4], bl[4];
#pragma unroll
        for (int i = 0; i < 2; ++i) {
            const int offA = (((wm << 5) + (i << 4) + lm) << 6) + chunkoff;
            ah[i] = *(const bf16x8*)(smem + offA);
            al[i] = *(const bf16x8*)(smem + 8192 + offA);
        }
#pragma unroll
        for (int j = 0; j < 4; ++j) {
            const int offB = (((wn << 6) + (j << 4) + lm) << 6) + chunkoff;
            bh[j] = *(const bf16x8*)(smem + 16384 + offB);
            bl[j] = *(const bf16x8*)(smem + 24576 + offB);
        }
#pragma unroll
        for (int i = 0; i < 2; ++i)
#pragma unroll
            for (int j = 0; j < 4; ++j) {
                acc[i][j] = __builtin_amdgcn_mfma_f32_16x16x32_bf16(ah[i], bh[j], acc[i][j], 0, 0, 0);
                acc[i][j] = __builtin_amdgcn_mfma_f32_16x16x32_bf16(ah[i], bl[j], acc[i][j], 0, 0, 0);
                acc[i][j] = __builtin_amdgcn_mfma_f32_16x16x32_bf16(al[i], bh[j], acc[i][j], 0, 0, 0);
            }
        __syncthreads();                          // reads done before next staging
    }

    // ---- epilogue ----
    const int bb = m0 >> 10, l0g = m0 & 1023, h0 = n0 >> 6;
    const int h = h0 + wn;                        // one wave-column = one head
    float* smf = (float*)smem;

    if (z < 2) {
        unsigned short* __restrict__ outhi = (z == 0) ? qhi : khi;
        unsigned short* __restrict__ outlo = (z == 0) ? qlo : klo;
        if (tid < 256) {  // per-row cos/sin/scale for both heads of this block
            const int row = tid & 127, hh = tid >> 7;
            const size_t pidx = ((size_t)(bb * NH + h0 + hh)) * SEQ + l0g + row;
            float s_, c_;
            sincosf(phi[pidx], &s_, &c_);
            smf[(hh << 7) + row] = c_;
            smf[256 + (hh << 7) + row] = s_;
            smf[512 + (hh << 7) + row] = 1.0f + gamma[h0 + hh] * tanhf(mag[pidx]);
        }
        __syncthreads();
        const size_t obase = (size_t)(bb * NH + h) * SEQ + l0g;
#pragma unroll
        for (int i = 0; i < 2; ++i)
#pragma unroll
            for (int r = 0; r < 4; ++r) {
                const int rowl = (wm << 5) + (i << 4) + (g << 2) + r;  // 0..127
                const float c_ = smf[(wn << 7) + rowl];
                const float s_ = smf[256 + (wn << 7) + rowl];
                const float sc = smf[512 + (wn << 7) + rowl];
                const size_t orow = (obase + rowl) * HDIM;
#pragma unroll
                for (int j = 0; j < 2; ++j) {     // d and d+32 = frags j, j+2
                    const int d = (j << 4) + lm;  // 0..31
                    const int n1 = n0 + (wn << 6) + d;
                    const float x1 = (acc[i][j][r] + bias[n1]) * sc;
                    const float x2 = (acc[i][j + 2][r] + bias[n1 + 32]) * sc;
                    const float o1 = x1 * c_ - x2 * s_;
                    const float o2 = x2 * c_ + x1 * s_;
                    const unsigned short h1 = bf16_bits(o1);
                    const unsigned short h2 = bf16_bits(o2);
                    outhi[orow + d]      = h1;
                    outlo[orow + d]      = bf16_bits(o1 - bf16_to_f(h1));
                    outhi[orow + d + 32] = h2;
                    outlo[orow + d + 32] = bf16_bits(o2 - bf16_to_f(h2));
                }
            }
    } else {
        const size_t obase = (size_t)(bb * NH + h) * SEQ + l0g;
#pragma unroll
        for (int i = 0; i < 2; ++i)
#pragma unroll
            for (int r = 0; r < 4; ++r) {
                const int rowl = (wm << 5) + (i << 4) + (g << 2) + r;
                const size_t orow = (obase + rowl) * HDIM;
#pragma unroll
                for (int j = 0; j < 4; ++j) {
                    const int d = (j << 4) + lm;  // 0..63
                    const float val = acc[i][j][r] + bias[n0 + (wn << 6) + d];
                    const unsigned short hv = bf16_bits(val);
                    const unsigned short lv = bf16_bits(val - bf16_to_f(hv));
                    vpack[orow + d] = (unsigned int)hv | ((unsigned int)lv << 16);
                }
            }
    }
}

// ---------------------------------------------------------------------------
// Global V transpose: vpack [bh][l][64] uint -> vthi/vtlo [bh][64][L] bf16.
// ---------------------------------------------------------------------------
__global__ __launch_bounds__(256) void vtrans_kernel(
    const unsigned int* __restrict__ vpack,
    unsigned short* __restrict__ vthi, unsigned short* __restrict__ vtlo)
{
    const int lt = blockIdx.x;    // 0..15 (l-tile)
    const int bh = blockIdx.y;    // 0..63
    __shared__ unsigned int Ts[64][65];
    const int t = threadIdx.x;
    const int row = t >> 2, c0 = (t & 3) << 4;   // row = l-local, c0 = d0
    const unsigned int* __restrict__ src =
        vpack + ((size_t)bh * SEQ + lt * 64 + row) * HDIM + c0;
#pragma unroll
    for (int i = 0; i < 4; ++i) {
        const u32x4 v = *(const u32x4*)(src + i * 4);
        Ts[row][c0 + i * 4 + 0] = v.x;
        Ts[row][c0 + i * 4 + 1] = v.y;
        Ts[row][c0 + i * 4 + 2] = v.z;
        Ts[row][c0 + i * 4 + 3] = v.w;
    }
    __syncthreads();
    const int dl = t >> 2, lc0 = (t & 3) << 4;   // dl = d-local, lc0 = l-local
    u16x8 h0, h1, l0v, l1v;
#pragma unroll
    for (int e = 0; e < 8; ++e) {
        const unsigned int u = Ts[lc0 + e][dl];
        h0[e]  = (unsigned short)(u & 0xffff);
        l0v[e] = (unsigned short)(u >> 16);
    }
#pragma unroll
    for (int e = 0; e < 8; ++e) {
        const unsigned int u = Ts[lc0 + 8 + e][dl];
        h1[e]  = (unsigned short)(u & 0xffff);
        l1v[e] = (unsigned short)(u >> 16);
    }
    const size_t orow = ((size_t)bh * HDIM + dl) * SEQ + lt * 64 + lc0;
    *(u16x8*)(vthi + orow)     = h0;
    *(u16x8*)(vthi + orow + 8) = h1;
    *(u16x8*)(vtlo + orow)     = l0v;
    *(u16x8*)(vtlo + orow + 8) = l1v;
}

// ---------------------------------------------------------------------------
// Flash attention on MFMA (split-bf16 QK^T and PV).
// Block = (q-tile of 64 rows) x (b,h).  4 waves x 16 q-rows, barrier-free
// between staging barriers -> waves at independent phases (T5 regime).
// ---------------------------------------------------------------------------
#define A_KHI 0
#define A_KLO 8192
#define A_VTH 16384
#define A_VTL 24576
#define A_P   32768          // + wid*4352 ; stride 68 uints per q-row

__global__ __launch_bounds__(256) void attn_mfma(
    const unsigned short* __restrict__ qhi, const unsigned short* __restrict__ qlo,
    const unsigned short* __restrict__ khi, const unsigned short* __restrict__ klo,
    const unsigned short* __restrict__ vthi, const unsigned short* __restrict__ vtlo,
    const float* __restrict__ mask,
    unsigned short* __restrict__ ctxhi, unsigned short* __restrict__ ctxlo)
{
    const int qt = blockIdx.x;        // 0..15
    const int bh = blockIdx.y;        // 0..63
    const int b = bh >> 4, h = bh & 15;
    const int tid = threadIdx.x, lane = tid & 63, wid = tid >> 6;
    const int lm = lane & 15, g = lane >> 4;

    __shared__ __align__(16) char smem[50176];
    unsigned int* pw = (unsigned int*)(smem + A_P + wid * 4352);

    // Q fragments (held for the whole block): rows q = wid*16 + lm
    bf16x8 qh[2], ql[2];
    {
        const size_t qr = ((size_t)bh * SEQ + qt * 64 + wid * 16 + lm) * HDIM;
#pragma unroll
        for (int c = 0; c < 2; ++c) {
            qh[c] = *(const bf16x8*)(qhi + qr + c * 32 + g * 8);
            ql[c] = *(const bf16x8*)(qlo + qr + c * 32 + g * 8);
        }
    }

    f32x4 caf[4] = {};                           // ctx d-frags
    float mrow[4] = {-3.0e38f, -3.0e38f, -3.0e38f, -3.0e38f};
    float lrow[4] = {};

    for (int kt = 0; kt < 16; ++kt) {
        __syncthreads();                         // previous tile reads done
#pragma unroll
        for (int s = 0; s < 8; ++s) {            // stage Khi,Klo,Vthi,Vtlo (8KB each)
            const int tile = s >> 1;
            const int c = ((s & 1) << 8) + tid;  // chunk 0..511
            const int row = c >> 3, ch = c & 7;
            const int sc = ch ^ (row & 7);       // inverse swizzle on source
            const unsigned short* src =
                (tile == 0) ? khi + ((size_t)bh * SEQ + kt * 64 + row) * HDIM + sc * 8 :
                (tile == 1) ? klo + ((size_t)bh * SEQ + kt * 64 + row) * HDIM + sc * 8 :
                (tile == 2) ? vthi + ((size_t)bh * HDIM + row) * SEQ + kt * 64 + sc * 8 :
                              vtlo + ((size_t)bh * HDIM + row) * SEQ + kt * 64 + sc * 8;
            gload16(src, smem + (tile << 13) + ((c & ~63) << 4));
        }
        __syncthreads();                         // tiles ready

        // ---- S = Q K^T (split-bf16), S[q=g*4+r][kv=f*16+lm] ----
        // attn tiles are [64 rows][64 bf16] = 128B rows, 8x16B chunks:
        // read chunk = ((dc<<2)+g) ^ (row&7)  (ldsfrag).
        f32x4 sf[4];
        __builtin_amdgcn_s_setprio(1);           // T5 (m191 +4-7%)
#pragma unroll
        for (int f = 0; f < 4; ++f) {
            f32x4 s = {};
#pragma unroll
            for (int c = 0; c < 2; ++c) {
                const bf16x8 kh = ldsfrag(smem + A_KHI, f * 16 + lm, c, g);
                const bf16x8 kl = ldsfrag(smem + A_KLO, f * 16 + lm, c, g);
                s = __builtin_amdgcn_mfma_f32_16x16x32_bf16(qh[c], kh, s, 0, 0, 0);
                s = __builtin_amdgcn_mfma_f32_16x16x32_bf16(qh[c], kl, s, 0, 0, 0);
                s = __builtin_amdgcn_mfma_f32_16x16x32_bf16(ql[c], kh, s, 0, 0, 0);
            }
            sf[f] = s;
        }
        __builtin_amdgcn_s_setprio(0);

        // ---- online softmax (rows q = g*4+r; cols f*16+lm) ----
        float mv[4];
#pragma unroll
        for (int f = 0; f < 4; ++f)
            mv[f] = mask[(size_t)b * SEQ + kt * 64 + f * 16 + lm];

        float sc_[4][4];
#pragma unroll
        for (int f = 0; f < 4; ++f)
#pragma unroll
            for (int r = 0; r < 4; ++r)
                sc_[f][r] = sf[f][r] * 0.125f + mv[f];

#pragma unroll
        for (int r = 0; r < 4; ++r) {
            float rm = fmaxf(fmaxf(sc_[0][r], sc_[1][r]), fmaxf(sc_[2][r], sc_[3][r]));
            rm = fmaxf(rm, __shfl_xor(rm, 1));
            rm = fmaxf(rm, __shfl_xor(rm, 2));
            rm = fmaxf(rm, __shfl_xor(rm, 4));
            rm = fmaxf(rm, __shfl_xor(rm, 8));
            const float mnew = fmaxf(mrow[r], rm);
            const float corr = __expf(mrow[r] - mnew);
            float p[4], sum = 0.f;
#pragma unroll
            for (int f = 0; f < 4; ++f) { p[f] = __expf(sc_[f][r] - mnew); sum += p[f]; }
            sum += __shfl_xor(sum, 1);
            sum += __shfl_xor(sum, 2);
            sum += __shfl_xor(sum, 4);
            sum += __shfl_xor(sum, 8);
            lrow[r] = lrow[r] * corr + sum;
            mrow[r] = mnew;
#pragma unroll
            for (int df = 0; df < 4; ++df) caf[df][r] *= corr;
#pragma unroll
            for (int f = 0; f < 4; ++f) {
                const unsigned short hv = bf16_bits(p[f]);
                const unsigned short lv = bf16_bits(p[f] - bf16_to_f(hv));
                pw[(g * 4 + r) * 68 + f * 16 + lm] =
                    (unsigned int)hv | ((unsigned int)lv << 16);
            }
        }

        // ---- P fragments (A-layout): row q = lm, kv = c*32 + g*8 + e ----
        bf16x8 ph[2], pl[2];
#pragma unroll
        for (int c = 0; c < 2; ++c) {
            const unsigned int* pr = pw + lm * 68 + c * 32 + g * 8;
            const u32x4 u0 = *(const u32x4*)pr;
            const u32x4 u1 = *(const u32x4*)(pr + 4);
            bf16x8 hh, ll;
            hh[0] = (short)(u0.x & 0xffff); ll[0] = (short)(u0.x >> 16);
            hh[1] = (short)(u0.y & 0xffff); ll[1] = (short)(u0.y >> 16);
            hh[2] = (short)(u0.z & 0xffff); ll[2] = (short)(u0.z >> 16);
            hh[3] = (short)(u0.w & 0xffff); ll[3] = (short)(u0.w >> 16);
            hh[4] = (short)(u1.x & 0xffff); ll[4] = (short)(u1.x >> 16);
            hh[5] = (short)(u1.y & 0xffff); ll[5] = (short)(u1.y >> 16);
            hh[6] = (short)(u1.z & 0xffff); ll[6] = (short)(u1.z >> 16);
            hh[7] = (short)(u1.w & 0xffff); ll[7] = (short)(u1.w >> 16);
            ph[c] = hh; pl[c] = ll;
        }

        // ---- ctx += P V (split-bf16) ----
        __builtin_amdgcn_s_setprio(1);
#pragma unroll
        for (int df = 0; df < 4; ++df)
#pragma unroll
            for (int c = 0; c < 2; ++c) {
                const bf16x8 vh = ldsfrag(smem + A_VTH, df * 16 + lm, c, g);
                const bf16x8 vl = ldsfrag(smem + A_VTL, df * 16 + lm, c, g);
                caf[df] = __builtin_amdgcn_mfma_f32_16x16x32_bf16(ph[c], vh, caf[df], 0, 0, 0);
                caf[df] = __builtin_amdgcn_mfma_f32_16x16x32_bf16(ph[c], vl, caf[df], 0, 0, 0);
                caf[df] = __builtin_amdgcn_mfma_f32_16x16x32_bf16(pl[c], vh, caf[df], 0, 0, 0);
            }
        __builtin_amdgcn_s_setprio(0);
    }

    // ---- write ctx (hi/lo planes, [B,L,D] with heads merged) ----
#pragma unroll
    for (int r = 0; r < 4; ++r) {
        const float inv = 1.0f / lrow[r];
        const size_t orow =
            ((size_t)b * SEQ + qt * 64 + wid * 16 + g * 4 + r) * DIM + h * HDIM;
#pragma unroll
        for (int df = 0; df < 4; ++df) {
            const float o = caf[df][r] * inv;
            const unsigned short hv = bf16_bits(o);
            ctxhi[orow + df * 16 + lm] = hv;
            ctxlo[orow + df * 16 + lm] = bf16_bits(o - bf16_to_f(hv));
        }
    }
}

// ---------------------------------------------------------------------------
// Out-projection GEMM: x = ctx @ Wo + bo + resid.  Same 8-wave core as qkv.
// ---------------------------------------------------------------------------
__global__ __launch_bounds__(512, 4) void out_gemm(
    const unsigned short* __restrict__ Ahi, const unsigned short* __restrict__ Alo,
    const unsigned short* __restrict__ Bhi, const unsigned short* __restrict__ Blo,
    const float* __restrict__ bo, const float* __restrict__ resid,
    float* __restrict__ xout)
{
    const int n0 = blockIdx.x * 128, m0 = blockIdx.y * 128;
    const int tid = threadIdx.x, lane = tid & 63, wid = tid >> 6;
    const int wm = wid >> 1, wn = wid & 1;
    const int lm = lane & 15, g = lane >> 4;
    const int sel = (lane >> 1) & 3;
    const int chunkoff = ((g ^ sel) << 4);

    __shared__ f32x4 smem_[2048];
    char* smem = (char*)smem_;

    f32x4 acc[2][4] = {};

    const int sm = tid >> 2, sj = tid & 3;
    const int skk = ((sj ^ ((sm >> 1) & 3)) << 3);
    const int sdst = (wid << 10);

    for (int k0 = 0; k0 < DIM; k0 += 32) {
#pragma unroll
        for (int t = 0; t < 4; ++t) {
            const unsigned short* srcrow =
                (t == 0) ? Ahi + (size_t)(m0 + sm) * DIM :
                (t == 1) ? Alo + (size_t)(m0 + sm) * DIM :
                (t == 2) ? Bhi + (size_t)(n0 + sm) * DIM :
                           Blo + (size_t)(n0 + sm) * DIM;
            gload16(srcrow + k0 + skk, smem + (t << 13) + sdst);
        }
        __syncthreads();

        bf16x8 ah[2], al[2], bh[4], bl[4];
#pragma unroll
        for (int i = 0; i < 2; ++i) {
            const int offA = (((wm << 5) + (i << 4) + lm) << 6) + chunkoff;
            ah[i] = *(const bf16x8*)(smem + offA);
            al[i] = *(const bf16x8*)(smem + 8192 + offA);
        }
#pragma unroll
        for (int j = 0; j < 4; ++j) {
            const int offB = (((wn << 6) + (j << 4) + lm) << 6) + chunkoff;
            bh[j] = *(const bf16x8*)(smem + 16384 + offB);
            bl[j] = *(const bf16x8*)(smem + 24576 + offB);
        }
#pragma unroll
        for (int i = 0; i < 2; ++i)
#pragma unroll
            for (int j = 0; j < 4; ++j) {
                acc[i][j] = __builtin_amdgcn_mfma_f32_16x16x32_bf16(ah[i], bh[j], acc[i][j], 0, 0, 0);
                acc[i][j] = __builtin_amdgcn_mfma_f32_16x16x32_bf16(ah[i], bl[j], acc[i][j], 0, 0, 0);
                acc[i][j] = __builtin_amdgcn_mfma_f32_16x16x32_bf16(al[i], bh[j], acc[i][j], 0, 0, 0);
            }
        __syncthreads();
    }

#pragma unroll
    for (int i = 0; i < 2; ++i)
#pragma unroll
        for (int r = 0; r < 4; ++r) {
            const int mrow = m0 + (wm << 5) + (i << 4) + (g << 2) + r;
#pragma unroll
            for (int j = 0; j < 4; ++j) {
                const int n1 = n0 + (wn << 6) + (j << 4) + lm;
                xout[(size_t)mrow * DIM + n1] =
                    acc[i][j][r] + bo[n1] + resid[(size_t)mrow * DIM + n1];
            }
        }
}

// ---------------------------------------------------------------------------
// LayerNorm over D=1024, one row per block.
// ---------------------------------------------------------------------------
__global__ __launch_bounds__(256) void ln_kernel(
    const float* __restrict__ x, const float* __restrict__ g,
    const float* __restrict__ bta, float* __restrict__ out)
{
    const int row = blockIdx.x;
    const int tid = threadIdx.x;
    const float4 xv = ((const float4*)(x + (size_t)row * DIM))[tid];
    float s  = xv.x + xv.y + xv.z + xv.w;
    float s2 = xv.x * xv.x + xv.y * xv.y + xv.z * xv.z + xv.w * xv.w;
#pragma unroll
    for (int off = 1; off < 64; off <<= 1) {
        s  += __shfl_xor(s, off, 64);
        s2 += __shfl_xor(s2, off, 64);
    }
    __shared__ float red[8];
    const int wv = tid >> 6;
    if ((tid & 63) == 0) { red[wv] = s; red[wv + 4] = s2; }
    __syncthreads();
    s  = red[0] + red[1] + red[2] + red[3];
    s2 = red[4] + red[5] + red[6] + red[7];
    const float mu   = s * (1.0f / DIM);
    const float var  = s2 * (1.0f / DIM) - mu * mu;
    const float rstd = 1.0f / sqrtf(var + 1e-12f);
    const float4 gv = ((const float4*)g)[tid];
    const float4 bv = ((const float4*)bta)[tid];
    float4 o;
    o.x = (xv.x - mu) * rstd * gv.x + bv.x;
    o.y = (xv.y - mu) * rstd * gv.y + bv.y;
    o.z = (xv.z - mu) * rstd * gv.z + bv.z;
    o.w = (xv.w - mu) * rstd * gv.w + bv.w;
    ((float4*)(out + (size_t)row * DIM))[tid] = o;
}

// ---------------------------------------------------------------------------
extern "C" void kernel_launch(void* const* d_in, const int* in_sizes, int n_in,
                              void* d_out, int out_size, void* d_ws, size_t ws_size,
                              hipStream_t stream)
{
    const float* X     = (const float*)d_in[0];
    const float* mask  = (const float*)d_in[1];
    const float* phi   = (const float*)d_in[2];
    const float* mag   = (const float*)d_in[3];
    const float* Wq    = (const float*)d_in[4];
    const float* bq    = (const float*)d_in[5];
    const float* Wk    = (const float*)d_in[6];
    const float* bk    = (const float*)d_in[7];
    const float* Wv    = (const float*)d_in[8];
    const float* bv    = (const float*)d_in[9];
    const float* gamma = (const float*)d_in[10];
    const float* Wo    = (const float*)d_in[11];
    const float* bo    = (const float*)d_in[12];
    const float* lsc   = (const float*)d_in[13];
    const float* lbi   = (const float*)d_in[14];
    float* out = (float*)d_out;

    char* w = (char*)d_ws;
    const size_t MB = 1048576;
    unsigned short* qhi   = (unsigned short*)(w + 0 * MB);    // 8 MB each
    unsigned short* qlo   = (unsigned short*)(w + 8 * MB);
    unsigned short* khi   = (unsigned short*)(w + 16 * MB);
    unsigned short* klo   = (unsigned short*)(w + 24 * MB);
    unsigned int*   vpack = (unsigned int*)  (w + 32 * MB);   // 16 MB
    float*          xbuf  = (float*)         (w + 32 * MB);   // aliases vpack (dead by then)
    unsigned short* vthi  = (unsigned short*)(w + 48 * MB);
    unsigned short* vtlo  = (unsigned short*)(w + 56 * MB);
    unsigned short* Xhi   = (unsigned short*)(w + 64 * MB);
    unsigned short* Xlo   = (unsigned short*)(w + 72 * MB);
    unsigned short* ctxhi = Xhi;                              // aliases (X split dead)
    unsigned short* ctxlo = Xlo;
    unsigned short* Wt    = (unsigned short*)(w + 80 * MB);   // 16 MB

    split_kernel<<<4096, 256, 0, stream>>>((const float4*)X, (ushort4*)Xhi, (ushort4*)Xlo);
    wsplit_kernel<<<dim3(32, 32, 4), 256, 0, stream>>>(Wq, Wk, Wv, Wo, Wt);
    qkv_gemm<<<dim3(8, 32, 3), 512, 0, stream>>>(
        Xhi, Xlo, Wt, bq, bk, bv, phi, mag, gamma, qhi, qlo, khi, klo, vpack);
    vtrans_kernel<<<dim3(16, 64), 256, 0, stream>>>(vpack, vthi, vtlo);
    attn_mfma<<<dim3(16, 64), 256, 0, stream>>>(
        qhi, qlo, khi, klo, vthi, vtlo, mask, ctxhi, ctxlo);
    out_gemm<<<dim3(8, 32), 512, 0, stream>>>(
        ctxhi, ctxlo, Wt + 6 * 1048576, Wt + 7 * 1048576, bo, X, xbuf);
    ln_kernel<<<4096, 256, 0, stream>>>(xbuf, lsc, lbi, out);
}

// Round 8
// 332.465 us; speedup vs baseline: 1.1138x; 1.0329x over previous
//
#include <hip/hip_runtime.h>
#include <hip/hip_bf16.h>
#include <cmath>

#define SEQ  1024
#define DIM  1024
#define NH   16
#define HDIM 64

typedef __attribute__((ext_vector_type(8))) short bf16x8;   // 8 bf16 (4 VGPRs)
typedef __attribute__((ext_vector_type(4))) float f32x4;    // MFMA accumulator
typedef __attribute__((ext_vector_type(4))) unsigned int u32x4;
typedef __attribute__((ext_vector_type(8))) unsigned short u16x8;

static __device__ __forceinline__ unsigned short bf16_bits(float x) {
    __hip_bfloat16 h = __float2bfloat16(x);
    union { __hip_bfloat16 b; unsigned short u; } cv; cv.b = h; return cv.u;
}
static __device__ __forceinline__ float bf16_to_f(unsigned short u) {
    union { unsigned short u; __hip_bfloat16 b; } cv; cv.u = u; return __bfloat162float(cv.b);
}

static __device__ __forceinline__ void gload16(const void* g, void* l) {
    __builtin_amdgcn_global_load_lds(
        (const __attribute__((address_space(1))) void*)g,
        (__attribute__((address_space(3))) void*)l, 16, 0, 0);
}

// Fragment read from a [rows][64 bf16] LDS tile (128B rows, 8x16B chunks),
// chunk-XOR swizzled (chunk ^= row&7).  HW-verified conflict-free (r4/r5).
static __device__ __forceinline__ bf16x8 ldsfrag(const char* base, int row, int dc, int g) {
    const int chunk = ((dc << 2) + g) ^ (row & 7);
    return *(const bf16x8*)(base + row * 128 + chunk * 16);
}

// ---------------------------------------------------------------------------
// Split fp32 -> (hi, lo) bf16 planes.  x == hi + lo to ~2^-16 rel.
// ---------------------------------------------------------------------------
__global__ __launch_bounds__(256) void split_kernel(
    const float4* __restrict__ src, ushort4* __restrict__ hi, ushort4* __restrict__ lo)
{
    const int i = blockIdx.x * 256 + threadIdx.x;
    const float4 v = src[i];
    ushort4 H, L;
    H.x = bf16_bits(v.x); L.x = bf16_bits(v.x - bf16_to_f(H.x));
    H.y = bf16_bits(v.y); L.y = bf16_bits(v.y - bf16_to_f(H.y));
    H.z = bf16_bits(v.z); L.z = bf16_bits(v.z - bf16_to_f(H.z));
    H.w = bf16_bits(v.w); L.w = bf16_bits(v.w - bf16_to_f(H.w));
    hi[i] = H; lo[i] = L;
}

// ---------------------------------------------------------------------------
// Transpose + split weights: W[k][n] fp32 -> Wt{hi,lo}[n][k] bf16.
// ---------------------------------------------------------------------------
__global__ __launch_bounds__(256) void wsplit_kernel(
    const float* __restrict__ Wq, const float* __restrict__ Wk,
    const float* __restrict__ Wv, const float* __restrict__ Wo,
    unsigned short* __restrict__ base)
{
    const int z = blockIdx.z;
    const float* __restrict__ W = (z == 0) ? Wq : (z == 1) ? Wk : (z == 2) ? Wv : Wo;
    unsigned short* __restrict__ hi = base + (size_t)z * 2097152;
    unsigned short* __restrict__ lo = hi + 1048576;
    const int k0 = blockIdx.y * 32, n0 = blockIdx.x * 32;
    __shared__ float Ts[32][33];
    const int t = threadIdx.x, r = t >> 5, c = t & 31;
#pragma unroll
    for (int s = 0; s < 4; ++s)
        Ts[r + 8 * s][c] = W[(size_t)(k0 + r + 8 * s) * DIM + n0 + c];
    __syncthreads();
#pragma unroll
    for (int s = 0; s < 4; ++s) {
        const int rr = r + 8 * s;            // n-local
        const float v = Ts[c][rr];           // = W[k0+c][n0+rr]
        const unsigned short h = bf16_bits(v);
        const unsigned short l = bf16_bits(v - bf16_to_f(h));
        hi[(size_t)(n0 + rr) * DIM + k0 + c] = h;
        lo[(size_t)(n0 + rr) * DIM + k0 + c] = l;
    }
}

// ---------------------------------------------------------------------------
// Split-bf16 MFMA GEMM, 128x128x32 block tile, 8 waves (4m x 2n),
// wave tile 32x64, acc = 2x4 frags.  16x16x32 bf16 MFMA.
// acc = Ahi*Bhi + Ahi*Blo + Alo*Bhi  (~1e-5 rel err).
// ---------------------------------------------------------------------------
__global__ __launch_bounds__(512, 4) void qkv_gemm(
    const unsigned short* __restrict__ Xhi, const unsigned short* __restrict__ Xlo,
    const unsigned short* __restrict__ Wt,
    const float* __restrict__ bq, const float* __restrict__ bk, const float* __restrict__ bv,
    const float* __restrict__ phi, const float* __restrict__ mag,
    const float* __restrict__ gamma,
    unsigned short* __restrict__ qhi, unsigned short* __restrict__ qlo,
    unsigned short* __restrict__ khi, unsigned short* __restrict__ klo,
    unsigned int* __restrict__ vpack)
{
    const int z = blockIdx.z;
    const unsigned short* __restrict__ Bhi = Wt + (size_t)z * 2097152;
    const unsigned short* __restrict__ Blo = Bhi + 1048576;
    const float* __restrict__ bias = (z == 0) ? bq : (z == 1) ? bk : bv;

    const int n0 = blockIdx.x * 128, m0 = blockIdx.y * 128;
    const int tid = threadIdx.x, lane = tid & 63, wid = tid >> 6;   // wid 0..7
    const int wm = wid >> 1, wn = wid & 1;
    const int lm = lane & 15, g = lane >> 4;
    const int sel = (lane >> 1) & 3;
    const int chunkoff = ((g ^ sel) << 4);

    __shared__ f32x4 smem_[2048];                 // 32 KB
    char* smem = (char*)smem_;

    f32x4 acc[2][4] = {};

    const int sm = tid >> 2, sj = tid & 3;
    const int skk = ((sj ^ ((sm >> 1) & 3)) << 3);
    const int sdst = (wid << 10);

    for (int k0 = 0; k0 < DIM; k0 += 32) {
#pragma unroll
        for (int t = 0; t < 4; ++t) {
            const unsigned short* srcrow =
                (t == 0) ? Xhi + (size_t)(m0 + sm) * DIM :
                (t == 1) ? Xlo + (size_t)(m0 + sm) * DIM :
                (t == 2) ? Bhi + (size_t)(n0 + sm) * DIM :
                           Blo + (size_t)(n0 + sm) * DIM;
            gload16(srcrow + k0 + skk, smem + (t << 13) + sdst);
        }
        __syncthreads();

        bf16x8 ah[2], al[2], bh[4], bl[4];
#pragma unroll
        for (int i = 0; i < 2; ++i) {
            const int offA = (((wm << 5) + (i << 4) + lm) << 6) + chunkoff;
            ah[i] = *(const bf16x8*)(smem + offA);
            al[i] = *(const bf16x8*)(smem + 8192 + offA);
        }
#pragma unroll
        for (int j = 0; j < 4; ++j) {
            const int offB = (((wn << 6) + (j << 4) + lm) << 6) + chunkoff;
            bh[j] = *(const bf16x8*)(smem + 16384 + offB);
            bl[j] = *(const bf16x8*)(smem + 24576 + offB);
        }
#pragma unroll
        for (int i = 0; i < 2; ++i)
#pragma unroll
            for (int j = 0; j < 4; ++j) {
                acc[i][j] = __builtin_amdgcn_mfma_f32_16x16x32_bf16(ah[i], bh[j], acc[i][j], 0, 0, 0);
                acc[i][j] = __builtin_amdgcn_mfma_f32_16x16x32_bf16(ah[i], bl[j], acc[i][j], 0, 0, 0);
                acc[i][j] = __builtin_amdgcn_mfma_f32_16x16x32_bf16(al[i], bh[j], acc[i][j], 0, 0, 0);
            }
        __syncthreads();
    }

    // ---- epilogue ----
    const int bb = m0 >> 10, l0g = m0 & 1023, h0 = n0 >> 6;
    const int h = h0 + wn;
    float* smf = (float*)smem;

    if (z < 2) {
        unsigned short* __restrict__ outhi = (z == 0) ? qhi : khi;
        unsigned short* __restrict__ outlo = (z == 0) ? qlo : klo;
        if (tid < 256) {
            const int row = tid & 127, hh = tid >> 7;
            const size_t pidx = ((size_t)(bb * NH + h0 + hh)) * SEQ + l0g + row;
            float s_, c_;
            sincosf(phi[pidx], &s_, &c_);
            smf[(hh << 7) + row] = c_;
            smf[256 + (hh << 7) + row] = s_;
            smf[512 + (hh << 7) + row] = 1.0f + gamma[h0 + hh] * tanhf(mag[pidx]);
        }
        __syncthreads();
        const size_t obase = (size_t)(bb * NH + h) * SEQ + l0g;
#pragma unroll
        for (int i = 0; i < 2; ++i)
#pragma unroll
            for (int r = 0; r < 4; ++r) {
                const int rowl = (wm << 5) + (i << 4) + (g << 2) + r;
                const float c_ = smf[(wn << 7) + rowl];
                const float s_ = smf[256 + (wn << 7) + rowl];
                const float sc = smf[512 + (wn << 7) + rowl];
                const size_t orow = (obase + rowl) * HDIM;
#pragma unroll
                for (int j = 0; j < 2; ++j) {
                    const int d = (j << 4) + lm;
                    const int n1 = n0 + (wn << 6) + d;
                    const float x1 = (acc[i][j][r] + bias[n1]) * sc;
                    const float x2 = (acc[i][j + 2][r] + bias[n1 + 32]) * sc;
                    const float o1 = x1 * c_ - x2 * s_;
                    const float o2 = x2 * c_ + x1 * s_;
                    const unsigned short h1 = bf16_bits(o1);
                    const unsigned short h2 = bf16_bits(o2);
                    outhi[orow + d]      = h1;
                    outlo[orow + d]      = bf16_bits(o1 - bf16_to_f(h1));
                    outhi[orow + d + 32] = h2;
                    outlo[orow + d + 32] = bf16_bits(o2 - bf16_to_f(h2));
                }
            }
    } else {
        const size_t obase = (size_t)(bb * NH + h) * SEQ + l0g;
#pragma unroll
        for (int i = 0; i < 2; ++i)
#pragma unroll
            for (int r = 0; r < 4; ++r) {
                const int rowl = (wm << 5) + (i << 4) + (g << 2) + r;
                const size_t orow = (obase + rowl) * HDIM;
#pragma unroll
                for (int j = 0; j < 4; ++j) {
                    const int d = (j << 4) + lm;
                    const float val = acc[i][j][r] + bias[n0 + (wn << 6) + d];
                    const unsigned short hv = bf16_bits(val);
                    const unsigned short lv = bf16_bits(val - bf16_to_f(hv));
                    vpack[orow + d] = (unsigned int)hv | ((unsigned int)lv << 16);
                }
            }
    }
}

// ---------------------------------------------------------------------------
// Global V transpose: vpack [bh][l][64] uint -> vthi/vtlo [bh][64][L] bf16.
// ---------------------------------------------------------------------------
__global__ __launch_bounds__(256) void vtrans_kernel(
    const unsigned int* __restrict__ vpack,
    unsigned short* __restrict__ vthi, unsigned short* __restrict__ vtlo)
{
    const int lt = blockIdx.x;
    const int bh = blockIdx.y;
    __shared__ unsigned int Ts[64][65];
    const int t = threadIdx.x;
    const int row = t >> 2, c0 = (t & 3) << 4;
    const unsigned int* __restrict__ src =
        vpack + ((size_t)bh * SEQ + lt * 64 + row) * HDIM + c0;
#pragma unroll
    for (int i = 0; i < 4; ++i) {
        const u32x4 v = *(const u32x4*)(src + i * 4);
        Ts[row][c0 + i * 4 + 0] = v.x;
        Ts[row][c0 + i * 4 + 1] = v.y;
        Ts[row][c0 + i * 4 + 2] = v.z;
        Ts[row][c0 + i * 4 + 3] = v.w;
    }
    __syncthreads();
    const int dl = t >> 2, lc0 = (t & 3) << 4;
    u16x8 h0, h1, l0v, l1v;
#pragma unroll
    for (int e = 0; e < 8; ++e) {
        const unsigned int u = Ts[lc0 + e][dl];
        h0[e]  = (unsigned short)(u & 0xffff);
        l0v[e] = (unsigned short)(u >> 16);
    }
#pragma unroll
    for (int e = 0; e < 8; ++e) {
        const unsigned int u = Ts[lc0 + 8 + e][dl];
        h1[e]  = (unsigned short)(u & 0xffff);
        l1v[e] = (unsigned short)(u >> 16);
    }
    const size_t orow = ((size_t)bh * HDIM + dl) * SEQ + lt * 64 + lc0;
    *(u16x8*)(vthi + orow)     = h0;
    *(u16x8*)(vthi + orow + 8) = h1;
    *(u16x8*)(vtlo + orow)     = l0v;
    *(u16x8*)(vtlo + orow + 8) = l1v;
}

// ---------------------------------------------------------------------------
// Flash attention on MFMA (split-bf16 QK^T and PV).
// QBLK=128, 8 waves (512 thr).  K/V staged once per 128 q-rows (halves
// staging vs QBLK=64), LDS exactly 64 KiB -> 2 blocks/CU under a 128 KiB
// budget (r5 evidence: 50176 B gave only 2 blocks -> occupancy 25%).
// P scratch: per-wave [16 q][64 kv] uints, stride 64, XOR swizzle
// phys_col = col ^ ((q&3)<<3)  (b128 reads 2-way = free; writes 4-way).
// ---------------------------------------------------------------------------
#define A_KHI 0
#define A_KLO 8192
#define A_VTH 16384
#define A_VTL 24576
#define A_P   32768          // + wid*4096

__global__ __launch_bounds__(512, 4) void attn_mfma(
    const unsigned short* __restrict__ qhi, const unsigned short* __restrict__ qlo,
    const unsigned short* __restrict__ khi, const unsigned short* __restrict__ klo,
    const unsigned short* __restrict__ vthi, const unsigned short* __restrict__ vtlo,
    const float* __restrict__ mask,
    unsigned short* __restrict__ ctxhi, unsigned short* __restrict__ ctxlo)
{
    const int qt = blockIdx.x;        // 0..7 (128-row q tiles)
    const int bh = blockIdx.y;        // 0..63
    const int b = bh >> 4, h = bh & 15;
    const int tid = threadIdx.x, lane = tid & 63, wid = tid >> 6;  // wid 0..7
    const int lm = lane & 15, g = lane >> 4;

    __shared__ __align__(16) char smem[65536];
    unsigned int* pw = (unsigned int*)(smem + A_P + (wid << 12));

    // Q fragments (held for the whole block): rows q = qt*128 + wid*16 + lm
    bf16x8 qh[2], ql[2];
    {
        const size_t qr = ((size_t)bh * SEQ + qt * 128 + wid * 16 + lm) * HDIM;
#pragma unroll
        for (int c = 0; c < 2; ++c) {
            qh[c] = *(const bf16x8*)(qhi + qr + c * 32 + g * 8);
            ql[c] = *(const bf16x8*)(qlo + qr + c * 32 + g * 8);
        }
    }

    f32x4 caf[4] = {};
    float mrow[4] = {-3.0e38f, -3.0e38f, -3.0e38f, -3.0e38f};
    float lrow[4] = {};

    // staging: 512 threads, 1 chunk per tile per thread
    const int sc_row = tid >> 3, sc_ch = tid & 7;
    const int sc_src = sc_ch ^ (sc_row & 7);           // inverse swizzle on source
    const int sc_dst = (tid & ~63) << 4;               // wave-uniform dest base

    for (int kt = 0; kt < 16; ++kt) {
        __syncthreads();                               // previous tile reads done
        {
            const unsigned short* k_base = khi + ((size_t)bh * SEQ + kt * 64 + sc_row) * HDIM + sc_src * 8;
            gload16(k_base, smem + A_KHI + sc_dst);
            const unsigned short* kl_base = klo + ((size_t)bh * SEQ + kt * 64 + sc_row) * HDIM + sc_src * 8;
            gload16(kl_base, smem + A_KLO + sc_dst);
            const unsigned short* vh_base = vthi + ((size_t)bh * HDIM + sc_row) * SEQ + kt * 64 + sc_src * 8;
            gload16(vh_base, smem + A_VTH + sc_dst);
            const unsigned short* vl_base = vtlo + ((size_t)bh * HDIM + sc_row) * SEQ + kt * 64 + sc_src * 8;
            gload16(vl_base, smem + A_VTL + sc_dst);
        }
        __syncthreads();                               // tiles ready

        // ---- S = Q K^T (split-bf16), S[q=g*4+r][kv=f*16+lm] ----
        f32x4 sf[4];
        __builtin_amdgcn_s_setprio(1);                 // T5
#pragma unroll
        for (int f = 0; f < 4; ++f) {
            f32x4 s = {};
#pragma unroll
            for (int c = 0; c < 2; ++c) {
                const bf16x8 kh = ldsfrag(smem + A_KHI, f * 16 + lm, c, g);
                const bf16x8 kl = ldsfrag(smem + A_KLO, f * 16 + lm, c, g);
                s = __builtin_amdgcn_mfma_f32_16x16x32_bf16(qh[c], kh, s, 0, 0, 0);
                s = __builtin_amdgcn_mfma_f32_16x16x32_bf16(qh[c], kl, s, 0, 0, 0);
                s = __builtin_amdgcn_mfma_f32_16x16x32_bf16(ql[c], kh, s, 0, 0, 0);
            }
            sf[f] = s;
        }
        __builtin_amdgcn_s_setprio(0);

        // ---- online softmax (rows q = g*4+r; cols f*16+lm) ----
        float mv[4];
#pragma unroll
        for (int f = 0; f < 4; ++f)
            mv[f] = mask[(size_t)b * SEQ + kt * 64 + f * 16 + lm];

        float sc_[4][4];
#pragma unroll
        for (int f = 0; f < 4; ++f)
#pragma unroll
            for (int r = 0; r < 4; ++r)
                sc_[f][r] = sf[f][r] * 0.125f + mv[f];

#pragma unroll
        for (int r = 0; r < 4; ++r) {
            float rm = fmaxf(fmaxf(sc_[0][r], sc_[1][r]), fmaxf(sc_[2][r], sc_[3][r]));
            rm = fmaxf(rm, __shfl_xor(rm, 1));
            rm = fmaxf(rm, __shfl_xor(rm, 2));
            rm = fmaxf(rm, __shfl_xor(rm, 4));
            rm = fmaxf(rm, __shfl_xor(rm, 8));
            const float mnew = fmaxf(mrow[r], rm);
            const float corr = __expf(mrow[r] - mnew);
            float p[4], sum = 0.f;
#pragma unroll
            for (int f = 0; f < 4; ++f) { p[f] = __expf(sc_[f][r] - mnew); sum += p[f]; }
            sum += __shfl_xor(sum, 1);
            sum += __shfl_xor(sum, 2);
            sum += __shfl_xor(sum, 4);
            sum += __shfl_xor(sum, 8);
            lrow[r] = lrow[r] * corr + sum;
            mrow[r] = mnew;
#pragma unroll
            for (int df = 0; df < 4; ++df) caf[df][r] *= corr;
#pragma unroll
            for (int f = 0; f < 4; ++f) {
                const unsigned short hv = bf16_bits(p[f]);
                const unsigned short lv = bf16_bits(p[f] - bf16_to_f(hv));
                pw[((g << 2) + r) * 64 + (((f << 4) + lm) ^ (r << 3))] =
                    (unsigned int)hv | ((unsigned int)lv << 16);
            }
        }

        // ---- P fragments (A-layout): row q = lm, kv = c*32 + g*8 + e ----
        bf16x8 ph[2], pl[2];
#pragma unroll
        for (int c = 0; c < 2; ++c) {
            const unsigned int* pr =
                pw + lm * 64 + (((c << 5) + (g << 3)) ^ ((lm & 3) << 3));
            const u32x4 u0 = *(const u32x4*)pr;
            const u32x4 u1 = *(const u32x4*)(pr + 4);
            bf16x8 hh, ll;
            hh[0] = (short)(u0.x & 0xffff); ll[0] = (short)(u0.x >> 16);
            hh[1] = (short)(u0.y & 0xffff); ll[1] = (short)(u0.y >> 16);
            hh[2] = (short)(u0.z & 0xffff); ll[2] = (short)(u0.z >> 16);
            hh[3] = (short)(u0.w & 0xffff); ll[3] = (short)(u0.w >> 16);
            hh[4] = (short)(u1.x & 0xffff); ll[4] = (short)(u1.x >> 16);
            hh[5] = (short)(u1.y & 0xffff); ll[5] = (short)(u1.y >> 16);
            hh[6] = (short)(u1.z & 0xffff); ll[6] = (short)(u1.z >> 16);
            hh[7] = (short)(u1.w & 0xffff); ll[7] = (short)(u1.w >> 16);
            ph[c] = hh; pl[c] = ll;
        }

        // ---- ctx += P V (split-bf16) ----
        __builtin_amdgcn_s_setprio(1);
#pragma unroll
        for (int df = 0; df < 4; ++df)
#pragma unroll
            for (int c = 0; c < 2; ++c) {
                const bf16x8 vh = ldsfrag(smem + A_VTH, df * 16 + lm, c, g);
                const bf16x8 vl = ldsfrag(smem + A_VTL, df * 16 + lm, c, g);
                caf[df] = __builtin_amdgcn_mfma_f32_16x16x32_bf16(ph[c], vh, caf[df], 0, 0, 0);
                caf[df] = __builtin_amdgcn_mfma_f32_16x16x32_bf16(ph[c], vl, caf[df], 0, 0, 0);
                caf[df] = __builtin_amdgcn_mfma_f32_16x16x32_bf16(pl[c], vh, caf[df], 0, 0, 0);
            }
        __builtin_amdgcn_s_setprio(0);
    }

    // ---- write ctx (hi/lo planes, [B,L,D] with heads merged) ----
#pragma unroll
    for (int r = 0; r < 4; ++r) {
        const float inv = 1.0f / lrow[r];
        const size_t orow =
            ((size_t)b * SEQ + qt * 128 + wid * 16 + g * 4 + r) * DIM + h * HDIM;
#pragma unroll
        for (int df = 0; df < 4; ++df) {
            const float o = caf[df][r] * inv;
            const unsigned short hv = bf16_bits(o);
            ctxhi[orow + df * 16 + lm] = hv;
            ctxlo[orow + df * 16 + lm] = bf16_bits(o - bf16_to_f(hv));
        }
    }
}

// ---------------------------------------------------------------------------
// Out-projection GEMM: x = ctx @ Wo + bo + resid.  Same 8-wave core as qkv.
// ---------------------------------------------------------------------------
__global__ __launch_bounds__(512, 4) void out_gemm(
    const unsigned short* __restrict__ Ahi, const unsigned short* __restrict__ Alo,
    const unsigned short* __restrict__ Bhi, const unsigned short* __restrict__ Blo,
    const float* __restrict__ bo, const float* __restrict__ resid,
    float* __restrict__ xout)
{
    const int n0 = blockIdx.x * 128, m0 = blockIdx.y * 128;
    const int tid = threadIdx.x, lane = tid & 63, wid = tid >> 6;
    const int wm = wid >> 1, wn = wid & 1;
    const int lm = lane & 15, g = lane >> 4;
    const int sel = (lane >> 1) & 3;
    const int chunkoff = ((g ^ sel) << 4);

    __shared__ f32x4 smem_[2048];
    char* smem = (char*)smem_;

    f32x4 acc[2][4] = {};

    const int sm = tid >> 2, sj = tid & 3;
    const int skk = ((sj ^ ((sm >> 1) & 3)) << 3);
    const int sdst = (wid << 10);

    for (int k0 = 0; k0 < DIM; k0 += 32) {
#pragma unroll
        for (int t = 0; t < 4; ++t) {
            const unsigned short* srcrow =
                (t == 0) ? Ahi + (size_t)(m0 + sm) * DIM :
                (t == 1) ? Alo + (size_t)(m0 + sm) * DIM :
                (t == 2) ? Bhi + (size_t)(n0 + sm) * DIM :
                           Blo + (size_t)(n0 + sm) * DIM;
            gload16(srcrow + k0 + skk, smem + (t << 13) + sdst);
        }
        __syncthreads();

        bf16x8 ah[2], al[2], bh[4], bl[4];
#pragma unroll
        for (int i = 0; i < 2; ++i) {
            const int offA = (((wm << 5) + (i << 4) + lm) << 6) + chunkoff;
            ah[i] = *(const bf16x8*)(smem + offA);
            al[i] = *(const bf16x8*)(smem + 8192 + offA);
        }
#pragma unroll
        for (int j = 0; j < 4; ++j) {
            const int offB = (((wn << 6) + (j << 4) + lm) << 6) + chunkoff;
            bh[j] = *(const bf16x8*)(smem + 16384 + offB);
            bl[j] = *(const bf16x8*)(smem + 24576 + offB);
        }
#pragma unroll
        for (int i = 0; i < 2; ++i)
#pragma unroll
            for (int j = 0; j < 4; ++j) {
                acc[i][j] = __builtin_amdgcn_mfma_f32_16x16x32_bf16(ah[i], bh[j], acc[i][j], 0, 0, 0);
                acc[i][j] = __builtin_amdgcn_mfma_f32_16x16x32_bf16(ah[i], bl[j], acc[i][j], 0, 0, 0);
                acc[i][j] = __builtin_amdgcn_mfma_f32_16x16x32_bf16(al[i], bh[j], acc[i][j], 0, 0, 0);
            }
        __syncthreads();
    }

#pragma unroll
    for (int i = 0; i < 2; ++i)
#pragma unroll
        for (int r = 0; r < 4; ++r) {
            const int mrow = m0 + (wm << 5) + (i << 4) + (g << 2) + r;
#pragma unroll
            for (int j = 0; j < 4; ++j) {
                const int n1 = n0 + (wn << 6) + (j << 4) + lm;
                xout[(size_t)mrow * DIM + n1] =
                    acc[i][j][r] + bo[n1] + resid[(size_t)mrow * DIM + n1];
            }
        }
}

// ---------------------------------------------------------------------------
// LayerNorm over D=1024, one row per block.
// ---------------------------------------------------------------------------
__global__ __launch_bounds__(256) void ln_kernel(
    const float* __restrict__ x, const float* __restrict__ g,
    const float* __restrict__ bta, float* __restrict__ out)
{
    const int row = blockIdx.x;
    const int tid = threadIdx.x;
    const float4 xv = ((const float4*)(x + (size_t)row * DIM))[tid];
    float s  = xv.x + xv.y + xv.z + xv.w;
    float s2 = xv.x * xv.x + xv.y * xv.y + xv.z * xv.z + xv.w * xv.w;
#pragma unroll
    for (int off = 1; off < 64; off <<= 1) {
        s  += __shfl_xor(s, off, 64);
        s2 += __shfl_xor(s2, off, 64);
    }
    __shared__ float red[8];
    const int wv = tid >> 6;
    if ((tid & 63) == 0) { red[wv] = s; red[wv + 4] = s2; }
    __syncthreads();
    s  = red[0] + red[1] + red[2] + red[3];
    s2 = red[4] + red[5] + red[6] + red[7];
    const float mu   = s * (1.0f / DIM);
    const float var  = s2 * (1.0f / DIM) - mu * mu;
    const float rstd = 1.0f / sqrtf(var + 1e-12f);
    const float4 gv = ((const float4*)g)[tid];
    const float4 bv = ((const float4*)bta)[tid];
    float4 o;
    o.x = (xv.x - mu) * rstd * gv.x + bv.x;
    o.y = (xv.y - mu) * rstd * gv.y + bv.y;
    o.z = (xv.z - mu) * rstd * gv.z + bv.z;
    o.w = (xv.w - mu) * rstd * gv.w + bv.w;
    ((float4*)(out + (size_t)row * DIM))[tid] = o;
}

// ---------------------------------------------------------------------------
extern "C" void kernel_launch(void* const* d_in, const int* in_sizes, int n_in,
                              void* d_out, int out_size, void* d_ws, size_t ws_size,
                              hipStream_t stream)
{
    const float* X     = (const float*)d_in[0];
    const float* mask  = (const float*)d_in[1];
    const float* phi   = (const float*)d_in[2];
    const float* mag   = (const float*)d_in[3];
    const float* Wq    = (const float*)d_in[4];
    const float* bq    = (const float*)d_in[5];
    const float* Wk    = (const float*)d_in[6];
    const float* bk    = (const float*)d_in[7];
    const float* Wv    = (const float*)d_in[8];
    const float* bv    = (const float*)d_in[9];
    const float* gamma = (const float*)d_in[10];
    const float* Wo    = (const float*)d_in[11];
    const float* bo    = (const float*)d_in[12];
    const float* lsc   = (const float*)d_in[13];
    const float* lbi   = (const float*)d_in[14];
    float* out = (float*)d_out;

    char* w = (char*)d_ws;
    const size_t MB = 1048576;
    unsigned short* qhi   = (unsigned short*)(w + 0 * MB);
    unsigned short* qlo   = (unsigned short*)(w + 8 * MB);
    unsigned short* khi   = (unsigned short*)(w + 16 * MB);
    unsigned short* klo   = (unsigned short*)(w + 24 * MB);
    unsigned int*   vpack = (unsigned int*)  (w + 32 * MB);
    float*          xbuf  = (float*)         (w + 32 * MB);   // aliases vpack (dead by then)
    unsigned short* vthi  = (unsigned short*)(w + 48 * MB);
    unsigned short* vtlo  = (unsigned short*)(w + 56 * MB);
    unsigned short* Xhi   = (unsigned short*)(w + 64 * MB);
    unsigned short* Xlo   = (unsigned short*)(w + 72 * MB);
    unsigned short* ctxhi = Xhi;                              // aliases (X split dead)
    unsigned short* ctxlo = Xlo;
    unsigned short* Wt    = (unsigned short*)(w + 80 * MB);

    split_kernel<<<4096, 256, 0, stream>>>((const float4*)X, (ushort4*)Xhi, (ushort4*)Xlo);
    wsplit_kernel<<<dim3(32, 32, 4), 256, 0, stream>>>(Wq, Wk, Wv, Wo, Wt);
    qkv_gemm<<<dim3(8, 32, 3), 512, 0, stream>>>(
        Xhi, Xlo, Wt, bq, bk, bv, phi, mag, gamma, qhi, qlo, khi, klo, vpack);
    vtrans_kernel<<<dim3(16, 64), 256, 0, stream>>>(vpack, vthi, vtlo);
    attn_mfma<<<dim3(8, 64), 512, 0, stream>>>(
        qhi, qlo, khi, klo, vthi, vtlo, mask, ctxhi, ctxlo);
    out_gemm<<<dim3(8, 32), 512, 0, stream>>>(
        ctxhi, ctxlo, Wt + 6 * 1048576, Wt + 7 * 1048576, bo, X, xbuf);
    ln_kernel<<<4096, 256, 0, stream>>>(xbuf, lsc, lbi, out);
}